// Round 1
// baseline (1208.501 us; speedup 1.0000x reference)
//
#include <hip/hip_runtime.h>
#include <hip/hip_bf16.h>
#include <math.h>

// Problem constants
#define BB 16
#define LL 128
#define HH 1024
#define VV 50257

// ---------------------------------------------------------------------------
// Kernel 1: x0 = relu(emb[input[:,0]]),  h0 = einsum(hidden, bridge_w) + bb
// 16384 threads, one per (b,h). Coalesced in h.
// ---------------------------------------------------------------------------
__global__ void k_embed_bridge(const int* __restrict__ input,
                               const float* __restrict__ hidden,
                               const float* __restrict__ emb,
                               const float* __restrict__ bw,
                               const float* __restrict__ bb,
                               float* __restrict__ x0,
                               float* __restrict__ h0) {
    int tid = blockIdx.x * 256 + threadIdx.x;     // 0..16383
    int b = tid >> 10;
    int h = tid & (HH - 1);
    int tok = input[b * LL];                      // input[b,0]
    float xv = emb[(long)tok * HH + h];
    x0[tid] = xv > 0.f ? xv : 0.f;                // b-major [b*H+h] == tid
    float acc = bb[0];
    const float* hp = hidden + (long)b * LL * HH + h;
    #pragma unroll 8
    for (int l = 0; l < LL; ++l) acc += hp[(long)l * HH] * bw[l];
    h0[tid] = acc;
}

// ---------------------------------------------------------------------------
// Kernel 2: gi_t[g*16+b] = x0[b]·w_ih[g] + b_ih[g]; gh_t same with h0,w_hh.
// Thread per (g,b), b = tid&15 so the 16 lanes sharing g broadcast-load the
// weight row (each of the 2x 12.6 MB weight matrices is fetched once).
// ---------------------------------------------------------------------------
__global__ void k_gates(const float* __restrict__ x0, const float* __restrict__ h0,
                        const float* __restrict__ w_ih, const float* __restrict__ w_hh,
                        const float* __restrict__ b_ih, const float* __restrict__ b_hh,
                        float* __restrict__ gi_t, float* __restrict__ gh_t) {
    int tid = blockIdx.x * 256 + threadIdx.x;     // 0..49151
    int g = tid >> 4;
    int b = tid & 15;
    const float4* wi = (const float4*)(w_ih + (long)g * HH);
    const float4* wh = (const float4*)(w_hh + (long)g * HH);
    const float4* xb = (const float4*)(x0 + b * HH);
    const float4* hb = (const float4*)(h0 + b * HH);
    float ai = 0.f, ah = 0.f;
    #pragma unroll 4
    for (int j = 0; j < HH / 4; ++j) {
        float4 w1 = wi[j], x = xb[j];
        ai += w1.x * x.x + w1.y * x.y + w1.z * x.z + w1.w * x.w;
        float4 w2 = wh[j], hv = hb[j];
        ah += w2.x * hv.x + w2.y * hv.y + w2.z * hv.z + w2.w * hv.w;
    }
    gi_t[tid] = ai + b_ih[g];                     // coalesced: addr == tid
    gh_t[tid] = ah + b_hh[g];
}

// ---------------------------------------------------------------------------
// Kernel 2b: GRU gate combine -> h1 [b-major]. 16384 threads.
// ---------------------------------------------------------------------------
__global__ void k_combine(const float* __restrict__ gi_t, const float* __restrict__ gh_t,
                          const float* __restrict__ h0, float* __restrict__ h1) {
    int tid = blockIdx.x * 256 + threadIdx.x;     // 0..16383
    int h = tid >> 4;
    int b = tid & 15;
    float ir = gi_t[h * 16 + b],          hr = gh_t[h * 16 + b];
    float iz = gi_t[(HH + h) * 16 + b],   hz = gh_t[(HH + h) * 16 + b];
    float in_ = gi_t[(2 * HH + h) * 16 + b], hn = gh_t[(2 * HH + h) * 16 + b];
    float r = 1.f / (1.f + expf(-(ir + hr)));
    float z = 1.f / (1.f + expf(-(iz + hz)));
    float n = tanhf(in_ + r * hn);
    float h0v = h0[b * HH + h];
    h1[b * HH + h] = (1.f - z) * n + z * h0v;
}

// ---------------------------------------------------------------------------
// Kernel 3: logits[b*V+v] = h1[b]·proj_w[v] + proj_b[v].
// Thread per (v,b); 16 lanes sharing v broadcast the proj_w float4 loads so
// the 206 MB matrix streams from HBM exactly once. h1 (64 KB) hits L2.
// ---------------------------------------------------------------------------
__global__ void k_logits(const float* __restrict__ h1,
                         const float* __restrict__ proj_w,
                         const float* __restrict__ proj_b,
                         float* __restrict__ logits) {
    int gtid = blockIdx.x * 256 + threadIdx.x;
    int v = gtid >> 4;
    int b = gtid & 15;
    if (v >= VV) return;
    const float4* w  = (const float4*)(proj_w + (long)v * HH);
    const float4* hb = (const float4*)(h1 + b * HH);
    float acc = 0.f;
    #pragma unroll 4
    for (int j = 0; j < HH / 4; ++j) {
        float4 wv = w[j], hv = hb[j];
        acc += wv.x * hv.x + wv.y * hv.y + wv.z * hv.z + wv.w * hv.w;
    }
    logits[(long)b * VV + v] = acc + proj_b[v];   // b-major for later passes
}

// ---------------------------------------------------------------------------
// Kernel 4: per-row log-sum-exp constant C[b] = max + log(sum exp(x-max)).
// 16 blocks (one per b), 256 threads, coalesced row scans.
// ---------------------------------------------------------------------------
__global__ void k_lse(const float* __restrict__ logits, float* __restrict__ C) {
    int b = blockIdx.x;
    int t = threadIdx.x;
    __shared__ float red[256];
    const float* row = logits + (long)b * VV;
    float m = -1e30f;
    for (int v = t; v < VV; v += 256) m = fmaxf(m, row[v]);
    red[t] = m; __syncthreads();
    for (int s = 128; s > 0; s >>= 1) {
        if (t < s) red[t] = fmaxf(red[t], red[t + s]);
        __syncthreads();
    }
    float M = red[0]; __syncthreads();
    float sum = 0.f;
    for (int v = t; v < VV; v += 256) sum += expf(row[v] - M);
    red[t] = sum; __syncthreads();
    for (int s = 128; s > 0; s >>= 1) {
        if (t < s) red[t] += red[t + s];
        __syncthreads();
    }
    if (t == 0) C[b] = M + logf(red[0]);
}

// ---------------------------------------------------------------------------
// Kernel 5: broadcast out[(b*127+t)*V + v] = logits[b*V+v] - C[b].
// grid (ceil(V/1024), 2032); logits stays L2-resident, pure write stream.
// ---------------------------------------------------------------------------
__global__ void k_bcast(const float* __restrict__ logits,
                        const float* __restrict__ C,
                        float* __restrict__ out) {
    int row = blockIdx.y;                         // 0..2031 = b*127 + t
    int b = row / (LL - 1);
    float c = C[b];
    const float* src = logits + (long)b * VV;
    float* dst = out + (long)row * VV;
    int v0 = blockIdx.x * 1024 + threadIdx.x;
    #pragma unroll
    for (int k = 0; k < 4; ++k) {
        int v = v0 + k * 256;
        if (v < VV) dst[v] = src[v] - c;
    }
}

extern "C" void kernel_launch(void* const* d_in, const int* in_sizes, int n_in,
                              void* d_out, int out_size, void* d_ws, size_t ws_size,
                              hipStream_t stream) {
    const int*   input    = (const int*)  d_in[0];
    const float* hidden   = (const float*)d_in[1];
    const float* emb      = (const float*)d_in[2];
    const float* bridge_w = (const float*)d_in[3];
    const float* bridge_b = (const float*)d_in[4];
    const float* w_ih     = (const float*)d_in[5];
    const float* w_hh     = (const float*)d_in[6];
    const float* b_ih     = (const float*)d_in[7];
    const float* b_hh     = (const float*)d_in[8];
    const float* proj_w   = (const float*)d_in[9];
    const float* proj_b   = (const float*)d_in[10];
    float* out = (float*)d_out;

    // Workspace layout (floats): all offsets 64-KB aligned where float4 needed
    float* ws     = (float*)d_ws;
    float* x0     = ws;                               // 16384
    float* h0     = ws + 16384;                       // 16384
    float* gi_t   = ws + 32768;                       // 49152
    float* gh_t   = ws + 81920;                       // 49152
    float* h1     = ws + 131072;                      // 16384
    float* logits = ws + 147456;                      // 16*50257 = 804112
    float* Cb     = ws + 147456 + 804112;             // 16

    k_embed_bridge<<<dim3(64), dim3(256), 0, stream>>>(input, hidden, emb,
                                                       bridge_w, bridge_b, x0, h0);
    k_gates<<<dim3(192), dim3(256), 0, stream>>>(x0, h0, w_ih, w_hh, b_ih, b_hh,
                                                 gi_t, gh_t);
    k_combine<<<dim3(64), dim3(256), 0, stream>>>(gi_t, gh_t, h0, h1);
    int nlog = VV * BB;                               // 804112
    k_logits<<<dim3((nlog + 255) / 256), dim3(256), 0, stream>>>(h1, proj_w,
                                                                 proj_b, logits);
    k_lse<<<dim3(BB), dim3(256), 0, stream>>>(logits, Cb);
    k_bcast<<<dim3(50, BB * (LL - 1)), dim3(256), 0, stream>>>(logits, Cb, out);
}